// Round 1
// baseline (21283.372 us; speedup 1.0000x reference)
//
#include <hip/hip_runtime.h>
#include <hip/hip_bf16.h>

typedef unsigned int uint;
typedef unsigned short ushort;
typedef __attribute__((ext_vector_type(8))) short short8;
typedef __attribute__((ext_vector_type(4))) float floatx4;

// Problem dims
#define BB 32
#define TT 448
#define DD 768
#define HH 256
#define G4 1024          // 4*H
#define BT 14336         // B*T

// Workspace layout (bytes), all 256-aligned
constexpr size_t OFF_XB   = 0;                        // x bf16: BT*D*2 = 22,020,096
constexpr size_t OFF_WIH  = 22020096;                 // wih bf16 (2,1024,768)*2B = 3,145,728
constexpr size_t OFF_WHH  = OFF_WIH + 3145728;        // whh bf16 (2,1024,256)*2B = 1,048,576
constexpr size_t OFF_BIAS = OFF_WHH + 1048576;        // bias f32 (2,1024)*4B = 8,192
constexpr size_t OFF_GX   = OFF_BIAS + 8192;          // gx f32 (2,BT,1024)*4B = 117,440,512
constexpr size_t OFF_LP   = OFF_GX + 117440512;       // lp f32 (2,B,T,2)*4B = 229,376
constexpr size_t OFF_KD   = OFF_LP + 229376;          // kd scalar

__device__ __forceinline__ ushort f2bf(float x) {
    uint u = __float_as_uint(x);
    uint r = (u + 0x7FFFu + ((u >> 16) & 1u)) >> 16;   // RNE, inputs are finite
    return (ushort)r;
}
__device__ __forceinline__ float bf2f(short s) {
    return __uint_as_float(((uint)(ushort)s) << 16);
}
__device__ __forceinline__ float sigm(float x) { return 1.0f / (1.0f + expf(-x)); }
__device__ __forceinline__ float lse2(float x, float y) {
    float m = fmaxf(x, y);
    return m + logf(expf(x - m) + expf(y - m));
}

// ---------------- K0: conversions + bias combine + zero kd ----------------
__global__ __launch_bounds__(256) void prep_kernel(
    const float* __restrict__ x,
    const float* __restrict__ wif, const float* __restrict__ wib,
    const float* __restrict__ whf, const float* __restrict__ whb,
    const float* __restrict__ bif, const float* __restrict__ bhf,
    const float* __restrict__ bib, const float* __restrict__ bhb,
    ushort* __restrict__ xb, ushort* __restrict__ wihb,
    ushort* __restrict__ whhb, float* __restrict__ bias,
    float* __restrict__ kd_sum)
{
    size_t i0 = (size_t)blockIdx.x * 256 + threadIdx.x;
    if (i0 == 0) kd_sum[0] = 0.f;
    const size_t NX = (size_t)BT * DD;        // 11,010,048
    const size_t NW = (size_t)G4 * DD;        // 786,432
    const size_t NH = (size_t)G4 * HH;        // 262,144
    const size_t TOT = NX + 2 * NW + 2 * NH + 2048;
    const size_t stride = (size_t)gridDim.x * 256;
    for (size_t idx = i0; idx < TOT; idx += stride) {
        if (idx < NX) {
            xb[idx] = f2bf(x[idx]);
        } else if (idx < NX + 2 * NW) {
            size_t j = idx - NX;
            wihb[j] = f2bf(j < NW ? wif[j] : wib[j - NW]);
        } else if (idx < NX + 2 * NW + 2 * NH) {
            size_t j = idx - NX - 2 * NW;
            whhb[j] = f2bf(j < NH ? whf[j] : whb[j - NH]);
        } else {
            size_t j = idx - NX - 2 * NW - 2 * NH;
            bias[j] = (j < 1024) ? (bif[j] + bhf[j]) : (bib[j - 1024] + bhb[j - 1024]);
        }
    }
}

// ---------------- K1: KD MSE reduction ----------------
__global__ __launch_bounds__(256) void kd_kernel(
    const float4* __restrict__ s, const float4* __restrict__ t,
    float* __restrict__ kd_sum, int n4)
{
    __shared__ float sred[4];
    float acc = 0.f;
    size_t stride = (size_t)gridDim.x * 256;
    for (size_t i = (size_t)blockIdx.x * 256 + threadIdx.x; i < (size_t)n4; i += stride) {
        float4 a = s[i], b = t[i];
        float d0 = a.x - b.x, d1 = a.y - b.y, d2 = a.z - b.z, d3 = a.w - b.w;
        acc += d0 * d0 + d1 * d1 + d2 * d2 + d3 * d3;
    }
    for (int off = 32; off; off >>= 1) acc += __shfl_down(acc, off, 64);
    int lane = threadIdx.x & 63, wv = threadIdx.x >> 6;
    if (lane == 0) sred[wv] = acc;
    __syncthreads();
    if (threadIdx.x == 0) atomicAdd(kd_sum, sred[0] + sred[1] + sred[2] + sred[3]);
}

// ---------------- K2: gx = x @ W_ih^T + (b_ih + b_hh), bf16 MFMA ----------------
// grid (224, 16, 2), block 256.  Block tile 64(M) x 64(N); wave = 16(M) x 64(N).
__global__ __launch_bounds__(256) void gemm_gx(
    const ushort* __restrict__ xb, const ushort* __restrict__ wih,
    const float* __restrict__ bias, float* __restrict__ gx)
{
    int dir = blockIdx.z;
    const ushort* W = wih + (size_t)dir * G4 * DD;
    float* out = gx + (size_t)dir * BT * G4;
    int tid = threadIdx.x;
    int wave = tid >> 6, lane = tid & 63;
    int quad = lane >> 4, r16 = lane & 15;
    int m0 = blockIdx.x * 64 + wave * 16;
    int n0 = blockIdx.y * 64;
    floatx4 acc[4];
    #pragma unroll
    for (int i = 0; i < 4; i++) acc[i] = (floatx4){0.f, 0.f, 0.f, 0.f};

    const ushort* aptr = xb + (size_t)(m0 + r16) * DD + quad * 8;
    const ushort* bptr = W + (size_t)(n0 + r16) * DD + quad * 8;
    for (int k = 0; k < DD; k += 32) {
        short8 af = *(const short8*)(aptr + k);
        #pragma unroll
        for (int nt = 0; nt < 4; nt++) {
            short8 bf = *(const short8*)(bptr + (size_t)nt * 16 * DD + k);
            acc[nt] = __builtin_amdgcn_mfma_f32_16x16x32_bf16(af, bf, acc[nt], 0, 0, 0);
        }
    }
    #pragma unroll
    for (int nt = 0; nt < 4; nt++) {
        int col = n0 + nt * 16 + r16;
        float bv = bias[dir * G4 + col];
        #pragma unroll
        for (int i = 0; i < 4; i++) {
            int row = m0 + quad * 4 + i;
            out[(size_t)row * G4 + col] = acc[nt][i] + bv;
        }
    }
}

// ---------------- K3: LSTM recurrence (one block per (dir,batch)) ----------------
// 1024 threads: thread = gate-row r in [0,1024); dim d = r&255, gate g = r>>8.
// h kept fp32 in LDS; W_hh bf16 streamed from L2; logits partials fused.
__global__ __launch_bounds__(1024) void lstm_rec(
    const float* __restrict__ gx, const ushort* __restrict__ whh,
    const float* __restrict__ Wcls, float* __restrict__ lp)
{
    int b = blockIdx.x, dir = blockIdx.y;
    int tid = threadIdx.x;
    int d = tid & 255;
    __shared__ float h_sh[256];
    __shared__ float g4s[1024];
    __shared__ float red[32];

    const float* gxb = gx + ((size_t)dir * BT + (size_t)b * TT) * G4;
    const ushort* Wr = whh + (size_t)dir * (G4 * HH) + (size_t)tid * HH;
    float wc0 = Wcls[dir * 256 + d];          // W_cls row 0, this dir's half
    float wc1 = Wcls[512 + dir * 256 + d];    // W_cls row 1
    float c = 0.f;
    if (tid < 256) h_sh[tid] = 0.f;
    __syncthreads();

    for (int s = 0; s < TT; s++) {
        int t = dir ? (TT - 1 - s) : s;
        float acc = gxb[(size_t)t * G4 + tid];
        for (int k = 0; k < HH; k += 8) {
            short8 w = *(const short8*)(Wr + k);
            #pragma unroll
            for (int j = 0; j < 8; j++) {
                acc += bf2f(w[j]) * h_sh[k + j];
            }
        }
        g4s[tid] = acc;
        __syncthreads();   // SYNC1: all h_sh reads + g4s writes done
        float h = 0.f;
        if (tid < 256) {
            float ig = sigm(g4s[d]);
            float fg = sigm(g4s[256 + d]);
            float gg = tanhf(g4s[512 + d]);
            float og = sigm(g4s[768 + d]);
            c = fg * c + ig * gg;
            h = og * tanhf(c);
            h_sh[d] = h;
        }
        float l0 = (tid < 256) ? h * wc0 : 0.f;
        float l1 = (tid < 256) ? h * wc1 : 0.f;
        for (int off = 32; off; off >>= 1) {
            l0 += __shfl_down(l0, off, 64);
            l1 += __shfl_down(l1, off, 64);
        }
        int lane = tid & 63, wv = tid >> 6;
        if (lane == 0) { red[wv * 2] = l0; red[wv * 2 + 1] = l1; }
        __syncthreads();   // SYNC2: h_sh + red visible
        if (tid == 0) {
            float s0 = 0.f, s1 = 0.f;
            #pragma unroll
            for (int w = 0; w < 16; w++) { s0 += red[w * 2]; s1 += red[w * 2 + 1]; }
            size_t o = ((size_t)(dir * BB + b) * TT + t) * 2;
            lp[o] = s0; lp[o + 1] = s1;
        }
    }
}

// ---------------- K4: CRF numerator + logZ + final loss ----------------
__global__ void crf_loss(
    const float* __restrict__ lp, const float* __restrict__ bcls,
    const float* __restrict__ cs, const float* __restrict__ ce,
    const float* __restrict__ ct, const int* __restrict__ labels,
    const int* __restrict__ mask, const float* __restrict__ kd_sum,
    float* __restrict__ out)
{
    int b = threadIdx.x;   // 64 threads, first 32 active
    float val = 0.f;
    if (b < BB) {
        const float* f0 = lp + (size_t)b * TT * 2;
        const float* b0 = lp + ((size_t)BB + b) * TT * 2;
        float bc0 = bcls[0], bc1 = bcls[1];
        float T00 = ct[0], T01 = ct[1], T10 = ct[2], T11 = ct[3];
        const int* lab = labels + (size_t)b * TT;
        const int* mk = mask + (size_t)b * TT;

        float e0 = f0[0] + b0[0] + bc0;
        float e1 = f0[1] + b0[1] + bc1;
        int y0 = lab[0];
        y0 = (y0 == -100) ? 0 : y0;
        float num = cs[y0] + (y0 ? e1 : e0);
        float a0 = cs[0] + e0, a1 = cs[1] + e1;
        int prev = y0;
        int msum = 1;   // mask[:,0] forced true
        for (int t = 1; t < TT; t++) {
            e0 = f0[t * 2] + b0[t * 2] + bc0;
            e1 = f0[t * 2 + 1] + b0[t * 2 + 1] + bc1;
            int y = lab[t];
            y = (y == -100) ? 0 : y;
            int mt = (mk[t] != 0);
            float mf = mt ? 1.f : 0.f;
            float trans = ct[prev * 2 + y];
            float em = y ? e1 : e0;
            num += (trans + em) * mf;
            float n0 = lse2(a0 + T00, a1 + T10) + e0;
            float n1 = lse2(a0 + T01, a1 + T11) + e1;
            if (mt) { a0 = n0; a1 = n1; }
            prev = y;
            msum += mt;
        }
        int last = lab[msum - 1];
        last = (last == -100) ? 0 : last;
        num += ce[last];
        float logZ = lse2(a0 + ce[0], a1 + ce[1]);
        val = num - logZ;
    }
    for (int off = 32; off; off >>= 1) val += __shfl_down(val, off, 64);
    if (threadIdx.x == 0) {
        float span = -(val / (float)BB);
        float kd = kd_sum[0] / (float)(3u * BB * TT * DD);
        out[0] = 0.5f * span + 0.5f * kd;
    }
}

extern "C" void kernel_launch(void* const* d_in, const int* in_sizes, int n_in,
                              void* d_out, int out_size, void* d_ws, size_t ws_size,
                              hipStream_t stream) {
    const float* x    = (const float*)d_in[0];
    const float* sf   = (const float*)d_in[1];
    const float* tfp  = (const float*)d_in[2];
    const float* wif  = (const float*)d_in[3];
    const float* whf  = (const float*)d_in[4];
    const float* bif  = (const float*)d_in[5];
    const float* bhf  = (const float*)d_in[6];
    const float* wib  = (const float*)d_in[7];
    const float* whb  = (const float*)d_in[8];
    const float* bib  = (const float*)d_in[9];
    const float* bhb  = (const float*)d_in[10];
    const float* wcls = (const float*)d_in[11];
    const float* bcls = (const float*)d_in[12];
    const float* cs   = (const float*)d_in[13];
    const float* ce   = (const float*)d_in[14];
    const float* ct   = (const float*)d_in[15];
    const int* labels = (const int*)d_in[16];
    const int* mask   = (const int*)d_in[17];
    float* out = (float*)d_out;

    char* ws = (char*)d_ws;
    ushort* xb   = (ushort*)(ws + OFF_XB);
    ushort* wihb = (ushort*)(ws + OFF_WIH);
    ushort* whhb = (ushort*)(ws + OFF_WHH);
    float* bias  = (float*)(ws + OFF_BIAS);
    float* gx    = (float*)(ws + OFF_GX);
    float* lp    = (float*)(ws + OFF_LP);
    float* kd    = (float*)(ws + OFF_KD);

    prep_kernel<<<1024, 256, 0, stream>>>(x, wif, wib, whf, whb, bif, bhf, bib, bhb,
                                          xb, wihb, whhb, bias, kd);
    kd_kernel<<<2048, 256, 0, stream>>>((const float4*)sf, (const float4*)tfp, kd,
                                        (int)(3u * BB * TT * DD / 4u));
    gemm_gx<<<dim3(224, 16, 2), 256, 0, stream>>>(xb, wihb, bias, gx);
    lstm_rec<<<dim3(BB, 2), 1024, 0, stream>>>(gx, whhb, wcls, lp);
    crf_loss<<<1, 64, 0, stream>>>(lp, bcls, cs, ce, ct, labels, mask, kd, out);
}

// Round 2
// 4171.715 us; speedup vs baseline: 5.1018x; 5.1018x over previous
//
#include <hip/hip_runtime.h>
#include <hip/hip_bf16.h>

typedef unsigned int uint;
typedef unsigned short ushort;
typedef __attribute__((ext_vector_type(8))) short short8;
typedef __attribute__((ext_vector_type(4))) float floatx4;

// Problem dims
#define BB 32
#define TT 448
#define DD 768
#define HH 256
#define G4 1024          // 4*H
#define BT 14336         // B*T
#define NBX 4            // blocks per direction in lstm_rec

// Workspace layout (bytes)
constexpr size_t OFF_XB   = 0;                        // x bf16: BT*D*2 = 22,020,096
constexpr size_t OFF_WIH  = 22020096;                 // wih bf16 (2,1024,768)*2B
constexpr size_t OFF_WHH  = OFF_WIH + 3145728;        // whh bf16 (2,1024,256)*2B
constexpr size_t OFF_BIAS = OFF_WHH + 1048576;        // bias f32 (2,1024)*4B
constexpr size_t OFF_GX   = OFF_BIAS + 8192;          // gx bf16 (2,BT,1024)*2B = 58,720,256
constexpr size_t OFF_HB   = OFF_GX + 58720256;        // hbuf bf16 (2,449,32,256)*2B = 14,712,832
constexpr size_t OFF_LP   = OFF_HB + 14712832;        // lp f32 (448,32,2)*4B = 114,688
constexpr size_t OFF_CNT  = OFF_LP + 114688;          // cnt int (2,449) padded to 1024 ints
constexpr size_t OFF_KD   = OFF_CNT + 4096;           // kd scalar

__device__ __forceinline__ ushort f2bf(float x) {
    uint u = __float_as_uint(x);
    uint r = (u + 0x7FFFu + ((u >> 16) & 1u)) >> 16;   // RNE, inputs finite
    return (ushort)r;
}
__device__ __forceinline__ float bf2f(short s) {
    return __uint_as_float(((uint)(ushort)s) << 16);
}
__device__ __forceinline__ float fsig(float x) {
    return __builtin_amdgcn_rcpf(1.0f + __expf(-x));
}
__device__ __forceinline__ float ftanh(float x) {
    return 2.0f * __builtin_amdgcn_rcpf(1.0f + __expf(-2.0f * x)) - 1.0f;
}
__device__ __forceinline__ float lse2(float x, float y) {
    float m = fmaxf(x, y);
    return m + logf(expf(x - m) + expf(y - m));
}

// ---------------- K0: conversions + bias combine + zero lp/cnt/kd ----------------
__global__ __launch_bounds__(256) void prep_kernel(
    const float* __restrict__ x,
    const float* __restrict__ wif, const float* __restrict__ wib,
    const float* __restrict__ whf, const float* __restrict__ whb,
    const float* __restrict__ bif, const float* __restrict__ bhf,
    const float* __restrict__ bib, const float* __restrict__ bhb,
    ushort* __restrict__ xb, ushort* __restrict__ wihb,
    ushort* __restrict__ whhb, float* __restrict__ bias,
    float* __restrict__ lp, int* __restrict__ cnt,
    float* __restrict__ kd_sum)
{
    size_t i0 = (size_t)blockIdx.x * 256 + threadIdx.x;
    if (i0 == 0) kd_sum[0] = 0.f;
    const size_t NX = (size_t)BT * DD;
    const size_t NW = (size_t)G4 * DD;
    const size_t NH = (size_t)G4 * HH;
    const size_t B0 = NX + 2 * NW + 2 * NH;      // bias base
    const size_t B1 = B0 + 2048;                 // lp base
    const size_t B2 = B1 + 28672;                // cnt base
    const size_t TOT = B2 + 1024;
    const size_t stride = (size_t)gridDim.x * 256;
    for (size_t idx = i0; idx < TOT; idx += stride) {
        if (idx < NX) {
            xb[idx] = f2bf(x[idx]);
        } else if (idx < NX + 2 * NW) {
            size_t j = idx - NX;
            wihb[j] = f2bf(j < NW ? wif[j] : wib[j - NW]);
        } else if (idx < NX + 2 * NW + 2 * NH) {
            size_t j = idx - NX - 2 * NW;
            whhb[j] = f2bf(j < NH ? whf[j] : whb[j - NH]);
        } else if (idx < B1) {
            size_t j = idx - B0;
            bias[j] = (j < 1024) ? (bif[j] + bhf[j]) : (bib[j - 1024] + bhb[j - 1024]);
        } else if (idx < B2) {
            lp[idx - B1] = 0.f;
        } else {
            cnt[idx - B2] = 0;
        }
    }
}

// ---------------- K1: KD MSE reduction ----------------
__global__ __launch_bounds__(256) void kd_kernel(
    const float4* __restrict__ s, const float4* __restrict__ t,
    float* __restrict__ kd_sum, int n4)
{
    __shared__ float sred[4];
    float acc = 0.f;
    size_t stride = (size_t)gridDim.x * 256;
    for (size_t i = (size_t)blockIdx.x * 256 + threadIdx.x; i < (size_t)n4; i += stride) {
        float4 a = s[i], b = t[i];
        float d0 = a.x - b.x, d1 = a.y - b.y, d2 = a.z - b.z, d3 = a.w - b.w;
        acc += d0 * d0 + d1 * d1 + d2 * d2 + d3 * d3;
    }
    for (int off = 32; off; off >>= 1) acc += __shfl_down(acc, off, 64);
    int lane = threadIdx.x & 63, wv = threadIdx.x >> 6;
    if (lane == 0) sred[wv] = acc;
    __syncthreads();
    if (threadIdx.x == 0) atomicAdd(kd_sum, sred[0] + sred[1] + sred[2] + sred[3]);
}

// ---------------- K2: gx = x @ W_ih^T + (b_ih + b_hh), bf16 MFMA, bf16 out ----------------
__global__ __launch_bounds__(256) void gemm_gx(
    const ushort* __restrict__ xb, const ushort* __restrict__ wih,
    const float* __restrict__ bias, ushort* __restrict__ gx)
{
    int dir = blockIdx.z;
    const ushort* W = wih + (size_t)dir * G4 * DD;
    ushort* out = gx + (size_t)dir * BT * G4;
    int tid = threadIdx.x;
    int wave = tid >> 6, lane = tid & 63;
    int quad = lane >> 4, r16 = lane & 15;
    int m0 = blockIdx.x * 64 + wave * 16;
    int n0 = blockIdx.y * 64;
    floatx4 acc[4];
    #pragma unroll
    for (int i = 0; i < 4; i++) acc[i] = (floatx4){0.f, 0.f, 0.f, 0.f};

    const ushort* aptr = xb + (size_t)(m0 + r16) * DD + quad * 8;
    const ushort* bptr = W + (size_t)(n0 + r16) * DD + quad * 8;
    for (int k = 0; k < DD; k += 32) {
        short8 af = *(const short8*)(aptr + k);
        #pragma unroll
        for (int nt = 0; nt < 4; nt++) {
            short8 bf = *(const short8*)(bptr + (size_t)nt * 16 * DD + k);
            acc[nt] = __builtin_amdgcn_mfma_f32_16x16x32_bf16(af, bf, acc[nt], 0, 0, 0);
        }
    }
    #pragma unroll
    for (int nt = 0; nt < 4; nt++) {
        int col = n0 + nt * 16 + r16;
        float bv = bias[dir * G4 + col];
        #pragma unroll
        for (int i = 0; i < 4; i++) {
            int row = m0 + quad * 4 + i;
            out[(size_t)row * G4 + col] = f2bf(acc[nt][i] + bv);
        }
    }
}

// ---------------- K3: LSTM recurrence, cooperative 4-blocks-per-dir ----------------
// grid (NBX, 2), block 256 = 4 waves, 1 wave/SIMD. W_hh slice register-resident:
// block bx owns dims d in [64*bx, 64*bx+64), all 4 gates (rows g*256+d of W_hh).
// Wave w owns j = d - 64*bx in [16w, 16w+16). Per step: M=32(batch) x N=64(its
// cols per wave, 4 gate-tiles) x K=256 MFMA; h exchanged via global hbuf with
// agent-scope release/acquire flags (cnt[dir][s] == NBX when h_s complete).
__global__ __launch_bounds__(256, 1) void lstm_rec(
    const ushort* __restrict__ gxall,   // [2][BT][1024] bf16
    const ushort* __restrict__ whhb,    // [2][1024][256] bf16
    const float* __restrict__ Wcls,     // [2][512] f32
    ushort* __restrict__ hbuf,          // [2][449][32][256] bf16
    int* __restrict__ cnt,              // [2][449]
    float* __restrict__ lp)             // [448][32][2] f32, atomic-accumulated
{
    int bx = blockIdx.x;
    int dir = blockIdx.y;
    int tid = threadIdx.x;
    int w = tid >> 6, lane = tid & 63;
    int quad = lane >> 4, r16 = lane & 15;
    int d = bx * 64 + w * 16 + r16;     // h-dim this lane's columns correspond to

    // W fragments: wfrag[g][kt] covers cols n=g-gate/dim d, k = kt*32 + quad*8 .. +8
    short8 wfrag[4][8];
    const ushort* wsrc = whhb + (size_t)dir * (G4 * HH);
    #pragma unroll
    for (int g = 0; g < 4; g++)
        #pragma unroll
        for (int kt = 0; kt < 8; kt++)
            wfrag[g][kt] = *(const short8*)(wsrc + (size_t)(g * 256 + d) * HH + kt * 32 + quad * 8);

    float wc0 = Wcls[dir * 256 + d];
    float wc1 = Wcls[512 + dir * 256 + d];
    float cst[2][4];
    #pragma unroll
    for (int mt = 0; mt < 2; mt++)
        #pragma unroll
        for (int r = 0; r < 4; r++) cst[mt][r] = 0.f;

    const ushort* gxd = gxall + (size_t)dir * BT * G4;
    ushort* hb = hbuf + (size_t)dir * 449 * BB * HH;
    int* cn = cnt + dir * 449;

    for (int s = 0; s < TT; s++) {
        int t = dir ? (TT - 1 - s) : s;
        // acc init from gx (issued before the flag poll; independent of h)
        floatx4 acc[4][2];
        #pragma unroll
        for (int g = 0; g < 4; g++)
            #pragma unroll
            for (int mt = 0; mt < 2; mt++)
                #pragma unroll
                for (int r = 0; r < 4; r++) {
                    int b = mt * 16 + quad * 4 + r;
                    acc[g][mt][r] = bf2f((short)gxd[((size_t)b * TT + t) * G4 + g * 256 + d]);
                }

        if (s > 0) {
            if (tid == 0) {
                while (__hip_atomic_load(&cn[s], __ATOMIC_ACQUIRE, __HIP_MEMORY_SCOPE_AGENT) < NBX) {}
            }
            __syncthreads();
            const ushort* hsrc = hb + (size_t)s * (BB * HH);
            #pragma unroll
            for (int kt = 0; kt < 8; kt++) {
                short8 a0 = *(const short8*)(hsrc + (size_t)(r16) * HH + kt * 32 + quad * 8);
                short8 a1 = *(const short8*)(hsrc + (size_t)(16 + r16) * HH + kt * 32 + quad * 8);
                #pragma unroll
                for (int g = 0; g < 4; g++) {
                    acc[g][0] = __builtin_amdgcn_mfma_f32_16x16x32_bf16(a0, wfrag[g][kt], acc[g][0], 0, 0, 0);
                    acc[g][1] = __builtin_amdgcn_mfma_f32_16x16x32_bf16(a1, wfrag[g][kt], acc[g][1], 0, 0, 0);
                }
            }
        }

        // Nonlinearities + h + logit partials.  b = mt*16 + quad*4 + r, col d.
        float lv0[2][4], lv1[2][4];
        ushort* hdst = hb + (size_t)(s + 1) * (BB * HH);
        #pragma unroll
        for (int mt = 0; mt < 2; mt++) {
            #pragma unroll
            for (int r = 0; r < 4; r++) {
                float ig = fsig(acc[0][mt][r]);
                float fg = fsig(acc[1][mt][r]);
                float gg = ftanh(acc[2][mt][r]);
                float og = fsig(acc[3][mt][r]);
                float c = fg * cst[mt][r] + ig * gg;
                cst[mt][r] = c;
                float h = og * ftanh(c);
                int b = mt * 16 + quad * 4 + r;
                hdst[(size_t)b * HH + d] = f2bf(h);
                lv0[mt][r] = h * wc0;
                lv1[mt][r] = h * wc1;
            }
        }
        // reduce logit partials over the 16 lanes (r16) sharing the same b-set
        #pragma unroll
        for (int off = 1; off < 16; off <<= 1) {
            #pragma unroll
            for (int mt = 0; mt < 2; mt++)
                #pragma unroll
                for (int r = 0; r < 4; r++) {
                    lv0[mt][r] += __shfl_xor(lv0[mt][r], off, 64);
                    lv1[mt][r] += __shfl_xor(lv1[mt][r], off, 64);
                }
        }
        if (r16 == 0) {
            #pragma unroll
            for (int mt = 0; mt < 2; mt++)
                #pragma unroll
                for (int r = 0; r < 4; r++) {
                    int b = mt * 16 + quad * 4 + r;
                    atomicAdd(&lp[((size_t)t * BB + b) * 2 + 0], lv0[mt][r]);
                    atomicAdd(&lp[((size_t)t * BB + b) * 2 + 1], lv1[mt][r]);
                }
        }
        __syncthreads();   // all h stores of this block complete (drained to L2)
        if (tid == 0) {
            __hip_atomic_fetch_add(&cn[s + 1], 1, __ATOMIC_RELEASE, __HIP_MEMORY_SCOPE_AGENT);
        }
    }
}

// ---------------- K4: CRF numerator + logZ + final loss ----------------
__global__ void crf_loss(
    const float* __restrict__ lp, const float* __restrict__ bcls,
    const float* __restrict__ cs, const float* __restrict__ ce,
    const float* __restrict__ ct, const int* __restrict__ labels,
    const int* __restrict__ mask, const float* __restrict__ kd_sum,
    float* __restrict__ out)
{
    int b = threadIdx.x;
    float val = 0.f;
    if (b < BB) {
        float bc0 = bcls[0], bc1 = bcls[1];
        float T00 = ct[0], T01 = ct[1], T10 = ct[2], T11 = ct[3];
        const int* lab = labels + (size_t)b * TT;
        const int* mk = mask + (size_t)b * TT;

        float e0 = lp[(size_t)b * 2 + 0] + bc0;
        float e1 = lp[(size_t)b * 2 + 1] + bc1;
        int y0 = lab[0];
        y0 = (y0 == -100) ? 0 : y0;
        float num = cs[y0] + (y0 ? e1 : e0);
        float a0 = cs[0] + e0, a1 = cs[1] + e1;
        int prev = y0;
        int msum = 1;
        for (int t = 1; t < TT; t++) {
            e0 = lp[((size_t)t * BB + b) * 2 + 0] + bc0;
            e1 = lp[((size_t)t * BB + b) * 2 + 1] + bc1;
            int y = lab[t];
            y = (y == -100) ? 0 : y;
            int mt = (mk[t] != 0);
            float mf = mt ? 1.f : 0.f;
            float trans = ct[prev * 2 + y];
            float em = y ? e1 : e0;
            num += (trans + em) * mf;
            float n0 = lse2(a0 + T00, a1 + T10) + e0;
            float n1 = lse2(a0 + T01, a1 + T11) + e1;
            if (mt) { a0 = n0; a1 = n1; }
            prev = y;
            msum += mt;
        }
        int last = lab[msum - 1];
        last = (last == -100) ? 0 : last;
        num += ce[last];
        float logZ = lse2(a0 + ce[0], a1 + ce[1]);
        val = num - logZ;
    }
    for (int off = 32; off; off >>= 1) val += __shfl_down(val, off, 64);
    if (threadIdx.x == 0) {
        float span = -(val / (float)BB);
        float kd = kd_sum[0] / (float)(3u * BB * TT * DD);
        out[0] = 0.5f * span + 0.5f * kd;
    }
}

extern "C" void kernel_launch(void* const* d_in, const int* in_sizes, int n_in,
                              void* d_out, int out_size, void* d_ws, size_t ws_size,
                              hipStream_t stream) {
    const float* x    = (const float*)d_in[0];
    const float* sf   = (const float*)d_in[1];
    const float* tfp  = (const float*)d_in[2];
    const float* wif  = (const float*)d_in[3];
    const float* whf  = (const float*)d_in[4];
    const float* bif  = (const float*)d_in[5];
    const float* bhf  = (const float*)d_in[6];
    const float* wib  = (const float*)d_in[7];
    const float* whb  = (const float*)d_in[8];
    const float* bib  = (const float*)d_in[9];
    const float* bhb  = (const float*)d_in[10];
    const float* wcls = (const float*)d_in[11];
    const float* bcls = (const float*)d_in[12];
    const float* cs   = (const float*)d_in[13];
    const float* ce   = (const float*)d_in[14];
    const float* ct   = (const float*)d_in[15];
    const int* labels = (const int*)d_in[16];
    const int* mask   = (const int*)d_in[17];
    float* out = (float*)d_out;

    char* ws = (char*)d_ws;
    ushort* xb   = (ushort*)(ws + OFF_XB);
    ushort* wihb = (ushort*)(ws + OFF_WIH);
    ushort* whhb = (ushort*)(ws + OFF_WHH);
    float* bias  = (float*)(ws + OFF_BIAS);
    ushort* gx   = (ushort*)(ws + OFF_GX);
    ushort* hbuf = (ushort*)(ws + OFF_HB);
    float* lp    = (float*)(ws + OFF_LP);
    int* cnt     = (int*)(ws + OFF_CNT);
    float* kd    = (float*)(ws + OFF_KD);

    prep_kernel<<<1024, 256, 0, stream>>>(x, wif, wib, whf, whb, bif, bhf, bib, bhb,
                                          xb, wihb, whhb, bias, lp, cnt, kd);
    kd_kernel<<<2048, 256, 0, stream>>>((const float4*)sf, (const float4*)tfp, kd,
                                        (int)(3u * BB * TT * DD / 4u));
    gemm_gx<<<dim3(224, 16, 2), 256, 0, stream>>>(xb, wihb, bias, gx);
    lstm_rec<<<dim3(NBX, 2), 256, 0, stream>>>(gx, whhb, wcls, hbuf, cnt, lp);
    crf_loss<<<1, 64, 0, stream>>>(lp, bcls, cs, ce, ct, labels, mask, kd, out);
}

// Round 6
// 2993.469 us; speedup vs baseline: 7.1099x; 1.3936x over previous
//
#include <hip/hip_runtime.h>
#include <hip/hip_bf16.h>

typedef unsigned int uint;
typedef unsigned short ushort;
typedef __attribute__((ext_vector_type(8))) short short8;
typedef __attribute__((ext_vector_type(4))) float floatx4;

// Problem dims
#define BB 32
#define TT 448
#define DD 768
#define HH 256
#define G4 1024          // 4*H
#define BT 14336         // B*T
#define NBX 4            // blocks per direction in lstm_rec
#define NWV 16           // waves per direction (NBX * 4)

// Workspace layout (bytes)
constexpr size_t OFF_XB   = 0;                        // x bf16: BT*D*2 = 22,020,096
constexpr size_t OFF_WIH  = 22020096;                 // wih bf16 (2,1024,768)*2B
constexpr size_t OFF_WHH  = OFF_WIH + 3145728;        // whh bf16 (2,1024,256)*2B
constexpr size_t OFF_BIAS = OFF_WHH + 1048576;        // bias f32 (2,1024)*4B
constexpr size_t OFF_GX   = OFF_BIAS + 8192;          // gx bf16 (2,T,B,1024)*2B = 58,720,256
constexpr size_t OFF_HB   = OFF_GX + 58720256;        // hbuf bf16 (2,449,32,256)*2B = 14,712,832
constexpr size_t OFF_LP   = OFF_HB + 14712832;        // lp f32 (448,32,2)*4B = 114,688
constexpr size_t OFF_CNT  = OFF_LP + 114688;          // cnt int (2,449) padded to 1024 ints
constexpr size_t OFF_KD   = OFF_CNT + 4096;           // kd scalar

__device__ __forceinline__ ushort f2bf(float x) {
    uint u = __float_as_uint(x);
    uint r = (u + 0x7FFFu + ((u >> 16) & 1u)) >> 16;   // RNE, inputs finite
    return (ushort)r;
}
__device__ __forceinline__ float bf2f(ushort s) {
    return __uint_as_float(((uint)s) << 16);
}
__device__ __forceinline__ float fsig(float x) {
    return __builtin_amdgcn_rcpf(1.0f + __expf(-x));
}
__device__ __forceinline__ float ftanh(float x) {
    return 2.0f * __builtin_amdgcn_rcpf(1.0f + __expf(-2.0f * x)) - 1.0f;
}
__device__ __forceinline__ float lse2(float x, float y) {
    float m = fmaxf(x, y);
    return m + logf(expf(x - m) + expf(y - m));
}

// Coherence-point store (bypasses L2 so remote XCDs see it without wbl2)
__device__ __forceinline__ void st_sc1_b64(void* addr, uint2 v) {
    asm volatile("global_store_dwordx2 %0, %1, off sc0 sc1" :: "v"(addr), "v"(v) : "memory");
}
// Coherence-point flag read: fresh value every call (no L2 staleness possible)
__device__ __forceinline__ int ld_flag_sc1(const int* addr) {
    int r;
    asm volatile("global_load_dword %0, %1, off sc0 sc1\n\t"
                 "s_waitcnt vmcnt(0)"
                 : "=&v"(r) : "v"(addr) : "memory");
    return r;
}
// Wait for all outstanding vector-memory ops (compiler-opaque stores included)
#define WAIT_VM0() asm volatile("s_waitcnt vmcnt(0)" ::: "memory")

// ---------------- K0: conversions + bias combine + zero lp/cnt/kd ----------------
__global__ __launch_bounds__(256) void prep_kernel(
    const float* __restrict__ x,
    const float* __restrict__ wif, const float* __restrict__ wib,
    const float* __restrict__ whf, const float* __restrict__ whb,
    const float* __restrict__ bif, const float* __restrict__ bhf,
    const float* __restrict__ bib, const float* __restrict__ bhb,
    ushort* __restrict__ xb, ushort* __restrict__ wihb,
    ushort* __restrict__ whhb, float* __restrict__ bias,
    float* __restrict__ lp, int* __restrict__ cnt,
    float* __restrict__ kd_sum)
{
    size_t i0 = (size_t)blockIdx.x * 256 + threadIdx.x;
    if (i0 == 0) kd_sum[0] = 0.f;
    const size_t NX = (size_t)BT * DD;
    const size_t NW = (size_t)G4 * DD;
    const size_t NH = (size_t)G4 * HH;
    const size_t B0 = NX + 2 * NW + 2 * NH;      // bias base
    const size_t B1 = B0 + 2048;                 // lp base
    const size_t B2 = B1 + 28672;                // cnt base
    const size_t TOT = B2 + 1024;
    const size_t stride = (size_t)gridDim.x * 256;
    for (size_t idx = i0; idx < TOT; idx += stride) {
        if (idx < NX) {
            xb[idx] = f2bf(x[idx]);
        } else if (idx < NX + 2 * NW) {
            size_t j = idx - NX;
            wihb[j] = f2bf(j < NW ? wif[j] : wib[j - NW]);
        } else if (idx < NX + 2 * NW + 2 * NH) {
            size_t j = idx - NX - 2 * NW;
            whhb[j] = f2bf(j < NH ? whf[j] : whb[j - NH]);
        } else if (idx < B1) {
            size_t j = idx - B0;
            bias[j] = (j < 1024) ? (bif[j] + bhf[j]) : (bib[j - 1024] + bhb[j - 1024]);
        } else if (idx < B2) {
            lp[idx - B1] = 0.f;
        } else {
            cnt[idx - B2] = 0;
        }
    }
}

// ---------------- K1: KD MSE reduction ----------------
__global__ __launch_bounds__(256) void kd_kernel(
    const float4* __restrict__ s, const float4* __restrict__ t,
    float* __restrict__ kd_sum, int n4)
{
    __shared__ float sred[4];
    float acc = 0.f;
    size_t stride = (size_t)gridDim.x * 256;
    for (size_t i = (size_t)blockIdx.x * 256 + threadIdx.x; i < (size_t)n4; i += stride) {
        float4 a = s[i], b = t[i];
        float d0 = a.x - b.x, d1 = a.y - b.y, d2 = a.z - b.z, d3 = a.w - b.w;
        acc += d0 * d0 + d1 * d1 + d2 * d2 + d3 * d3;
    }
    for (int off = 32; off; off >>= 1) acc += __shfl_down(acc, off, 64);
    int lane = threadIdx.x & 63, wv = threadIdx.x >> 6;
    if (lane == 0) sred[wv] = acc;
    __syncthreads();
    if (threadIdx.x == 0) atomicAdd(kd_sum, sred[0] + sred[1] + sred[2] + sred[3]);
}

// ---------------- K2: gx = x @ W_ih^T + bias, bf16 MFMA, out layout [dir][t][b][1024] ----------------
__global__ __launch_bounds__(256) void gemm_gx(
    const ushort* __restrict__ xb, const ushort* __restrict__ wih,
    const float* __restrict__ bias, ushort* __restrict__ gx)
{
    int dir = blockIdx.z;
    const ushort* W = wih + (size_t)dir * G4 * DD;
    ushort* out = gx + (size_t)dir * BT * G4;
    int tid = threadIdx.x;
    int wave = tid >> 6, lane = tid & 63;
    int quad = lane >> 4, r16 = lane & 15;
    int m0 = blockIdx.x * 64 + wave * 16;
    int n0 = blockIdx.y * 64;
    floatx4 acc[4];
    #pragma unroll
    for (int i = 0; i < 4; i++) acc[i] = (floatx4){0.f, 0.f, 0.f, 0.f};

    const ushort* aptr = xb + (size_t)(m0 + r16) * DD + quad * 8;
    const ushort* bptr = W + (size_t)(n0 + r16) * DD + quad * 8;
    for (int k = 0; k < DD; k += 32) {
        short8 af = *(const short8*)(aptr + k);
        #pragma unroll
        for (int nt = 0; nt < 4; nt++) {
            short8 bf = *(const short8*)(bptr + (size_t)nt * 16 * DD + k);
            acc[nt] = __builtin_amdgcn_mfma_f32_16x16x32_bf16(af, bf, acc[nt], 0, 0, 0);
        }
    }
    #pragma unroll
    for (int nt = 0; nt < 4; nt++) {
        int col = n0 + nt * 16 + r16;
        float bv = bias[dir * G4 + col];
        #pragma unroll
        for (int i = 0; i < 4; i++) {
            int row = m0 + quad * 4 + i;
            int b = row / TT, t = row % TT;     // tiles never straddle b (448 = 7*64)
            out[((size_t)t * BB + b) * G4 + col] = f2bf(acc[nt][i] + bv);
        }
    }
}

// ---------------- K3: LSTM recurrence, wave-autonomous, sc1 h-exchange ----------------
// grid (NBX,2) x 256 thr.  Wave (bx,w) owns d-slice dbase..dbase+15, all 4 gates.
// A = W_hh fragments (register-resident), B = h fragments (sc1 loads), D = gates^T.
// Per wave/step: 64 MFMA 16x16x32.  No __syncthreads in the loop; per-wave flag adds.
__global__ __launch_bounds__(256, 1) void lstm_rec(
    const ushort* __restrict__ gxall,   // [2][T][B][1024] bf16
    const ushort* __restrict__ whhb,    // [2][1024][256] bf16
    const float* __restrict__ Wcls,     // [2][512] f32
    ushort* __restrict__ hbuf,          // [2][449][32][256] bf16
    int* __restrict__ cnt,              // [2][449]
    float* __restrict__ lp)             // [448][32][2] f32, atomic-accumulated
{
    int bx = blockIdx.x;
    int dir = blockIdx.y;
    int tid = threadIdx.x;
    int w = tid >> 6, lane = tid & 63;
    int quad = lane >> 4, r16 = lane & 15;
    int dbase = bx * 64 + w * 16;       // this wave's 16 h-dims

    // A-operand W fragments: A[m=r16][k=kt*32+quad*8+j], row = g*256+dbase+r16
    short8 wfrag[4][8];
    const ushort* wsrc = whhb + (size_t)dir * (G4 * HH);
    #pragma unroll
    for (int g = 0; g < 4; g++)
        #pragma unroll
        for (int kt = 0; kt < 8; kt++)
            wfrag[g][kt] = *(const short8*)(wsrc + (size_t)(g * 256 + dbase + r16) * HH + kt * 32 + quad * 8);

    float wc0[4], wc1[4];
    #pragma unroll
    for (int r = 0; r < 4; r++) {
        int d = dbase + quad * 4 + r;
        wc0[r] = Wcls[dir * 256 + d];
        wc1[r] = Wcls[512 + dir * 256 + d];
    }
    float cst[2][4];
    #pragma unroll
    for (int mt = 0; mt < 2; mt++)
        #pragma unroll
        for (int r = 0; r < 4; r++) cst[mt][r] = 0.f;

    const ushort* gxd = gxall + (size_t)dir * BT * G4;
    ushort* hb = hbuf + (size_t)dir * 449 * BB * HH;
    int* cn = cnt + dir * 449;

    for (int s = 0; s < TT; s++) {
        int t = dir ? (TT - 1 - s) : s;
        // gx prefetch (issued before the poll; compiler waits at first use)
        uint2 gxv[4][2];
        #pragma unroll
        for (int g = 0; g < 4; g++)
            #pragma unroll
            for (int mt = 0; mt < 2; mt++)
                gxv[g][mt] = *(const uint2*)(gxd + ((size_t)t * BB + mt * 16 + r16) * G4
                                             + g * 256 + dbase + quad * 4);

        floatx4 acc[4][2];
        #pragma unroll
        for (int g = 0; g < 4; g++)
            #pragma unroll
            for (int mt = 0; mt < 2; mt++)
                acc[g][mt] = (floatx4){
                    bf2f((ushort)(gxv[g][mt].x & 0xFFFFu)),
                    bf2f((ushort)(gxv[g][mt].x >> 16)),
                    bf2f((ushort)(gxv[g][mt].y & 0xFFFFu)),
                    bf2f((ushort)(gxv[g][mt].y >> 16))};

        if (s > 0) {
            while (ld_flag_sc1(&cn[s]) < NWV) {}
            const ushort* hsrc = hb + (size_t)s * (BB * HH);
            const ushort* h0 = hsrc + (size_t)r16 * HH + quad * 8;
            const ushort* h1 = hsrc + (size_t)(16 + r16) * HH + quad * 8;
            int4 hA0, hA1, hA2, hA3, hA4, hA5, hA6, hA7;
            int4 hB0, hB1, hB2, hB3, hB4, hB5, hB6, hB7;
            // One asm block: 16 coherence-point loads + waitcnt. Early-clobber
            // outputs ("=&v") keep them disjoint from the address inputs
            // (plain "=v" let the allocator alias output regs onto %16/%17 ->
            // corrupted addresses -> GPU fault). MFMAs below data-depend on
            // these outputs, so they can't be hoisted above the in-block wait.
            asm volatile(
                "global_load_dwordx4 %0, %16, off sc0 sc1\n\t"
                "global_load_dwordx4 %1, %16, off offset:64 sc0 sc1\n\t"
                "global_load_dwordx4 %2, %16, off offset:128 sc0 sc1\n\t"
                "global_load_dwordx4 %3, %16, off offset:192 sc0 sc1\n\t"
                "global_load_dwordx4 %4, %16, off offset:256 sc0 sc1\n\t"
                "global_load_dwordx4 %5, %16, off offset:320 sc0 sc1\n\t"
                "global_load_dwordx4 %6, %16, off offset:384 sc0 sc1\n\t"
                "global_load_dwordx4 %7, %16, off offset:448 sc0 sc1\n\t"
                "global_load_dwordx4 %8, %17, off sc0 sc1\n\t"
                "global_load_dwordx4 %9, %17, off offset:64 sc0 sc1\n\t"
                "global_load_dwordx4 %10, %17, off offset:128 sc0 sc1\n\t"
                "global_load_dwordx4 %11, %17, off offset:192 sc0 sc1\n\t"
                "global_load_dwordx4 %12, %17, off offset:256 sc0 sc1\n\t"
                "global_load_dwordx4 %13, %17, off offset:320 sc0 sc1\n\t"
                "global_load_dwordx4 %14, %17, off offset:384 sc0 sc1\n\t"
                "global_load_dwordx4 %15, %17, off offset:448 sc0 sc1\n\t"
                "s_waitcnt vmcnt(0)"
                : "=&v"(hA0), "=&v"(hA1), "=&v"(hA2), "=&v"(hA3),
                  "=&v"(hA4), "=&v"(hA5), "=&v"(hA6), "=&v"(hA7),
                  "=&v"(hB0), "=&v"(hB1), "=&v"(hB2), "=&v"(hB3),
                  "=&v"(hB4), "=&v"(hB5), "=&v"(hB6), "=&v"(hB7)
                : "v"(h0), "v"(h1)
                : "memory");
            short8 hf[2][8];
            hf[0][0] = *(short8*)&hA0; hf[0][1] = *(short8*)&hA1;
            hf[0][2] = *(short8*)&hA2; hf[0][3] = *(short8*)&hA3;
            hf[0][4] = *(short8*)&hA4; hf[0][5] = *(short8*)&hA5;
            hf[0][6] = *(short8*)&hA6; hf[0][7] = *(short8*)&hA7;
            hf[1][0] = *(short8*)&hB0; hf[1][1] = *(short8*)&hB1;
            hf[1][2] = *(short8*)&hB2; hf[1][3] = *(short8*)&hB3;
            hf[1][4] = *(short8*)&hB4; hf[1][5] = *(short8*)&hB5;
            hf[1][6] = *(short8*)&hB6; hf[1][7] = *(short8*)&hB7;
            #pragma unroll
            for (int kt = 0; kt < 8; kt++)
                #pragma unroll
                for (int g = 0; g < 4; g++)
                    #pragma unroll
                    for (int mt = 0; mt < 2; mt++)
                        acc[g][mt] = __builtin_amdgcn_mfma_f32_16x16x32_bf16(
                            wfrag[g][kt], hf[mt][kt], acc[g][mt], 0, 0, 0);
        }

        // Epilogue: D row (quad*4+r) = d-offset, col r16 = batch (mt picks b or b+16)
        ushort* hdst = hb + (size_t)(s + 1) * (BB * HH);
        float lv0[2], lv1[2];
        #pragma unroll
        for (int mt = 0; mt < 2; mt++) {
            float l0 = 0.f, l1 = 0.f;
            uint pk[2];
            #pragma unroll
            for (int r = 0; r < 4; r++) {
                float ig = fsig(acc[0][mt][r]);
                float fg = fsig(acc[1][mt][r]);
                float gg = ftanh(acc[2][mt][r]);
                float og = fsig(acc[3][mt][r]);
                float c = fg * cst[mt][r] + ig * gg;
                cst[mt][r] = c;
                float h = og * ftanh(c);
                uint hb16 = (uint)f2bf(h);
                if (r & 1) pk[r >> 1] |= hb16 << 16; else pk[r >> 1] = hb16;
                l0 += h * wc0[r];
                l1 += h * wc1[r];
            }
            st_sc1_b64(hdst + (size_t)(mt * 16 + r16) * HH + dbase + quad * 4,
                       make_uint2(pk[0], pk[1]));
            lv0[mt] = l0; lv1[mt] = l1;
        }
        WAIT_VM0();   // h stores acked at coherence point before flag
        __hip_atomic_fetch_add(&cn[s + 1], 1, __ATOMIC_RELAXED, __HIP_MEMORY_SCOPE_AGENT);

        // logit partials: reduce over quad (lanes differing in bits 4,5), off critical path
        #pragma unroll
        for (int mt = 0; mt < 2; mt++) {
            lv0[mt] += __shfl_xor(lv0[mt], 16, 64);
            lv0[mt] += __shfl_xor(lv0[mt], 32, 64);
            lv1[mt] += __shfl_xor(lv1[mt], 16, 64);
            lv1[mt] += __shfl_xor(lv1[mt], 32, 64);
        }
        if (quad == 0) {
            #pragma unroll
            for (int mt = 0; mt < 2; mt++) {
                int b = mt * 16 + r16;
                atomicAdd(&lp[((size_t)t * BB + b) * 2 + 0], lv0[mt]);
                atomicAdd(&lp[((size_t)t * BB + b) * 2 + 1], lv1[mt]);
            }
        }
    }
}

// ---------------- K4: CRF numerator + logZ + final loss ----------------
__global__ void crf_loss(
    const float* __restrict__ lp, const float* __restrict__ bcls,
    const float* __restrict__ cs, const float* __restrict__ ce,
    const float* __restrict__ ct, const int* __restrict__ labels,
    const int* __restrict__ mask, const float* __restrict__ kd_sum,
    float* __restrict__ out)
{
    int b = threadIdx.x;
    float val = 0.f;
    if (b < BB) {
        float bc0 = bcls[0], bc1 = bcls[1];
        float T00 = ct[0], T01 = ct[1], T10 = ct[2], T11 = ct[3];
        const int* lab = labels + (size_t)b * TT;
        const int* mk = mask + (size_t)b * TT;

        float e0 = lp[(size_t)b * 2 + 0] + bc0;
        float e1 = lp[(size_t)b * 2 + 1] + bc1;
        int y0 = lab[0];
        y0 = (y0 == -100) ? 0 : y0;
        float num = cs[y0] + (y0 ? e1 : e0);
        float a0 = cs[0] + e0, a1 = cs[1] + e1;
        int prev = y0;
        int msum = 1;
        for (int t = 1; t < TT; t++) {
            e0 = lp[((size_t)t * BB + b) * 2 + 0] + bc0;
            e1 = lp[((size_t)t * BB + b) * 2 + 1] + bc1;
            int y = lab[t];
            y = (y == -100) ? 0 : y;
            int mt = (mk[t] != 0);
            float mf = mt ? 1.f : 0.f;
            float trans = ct[prev * 2 + y];
            float em = y ? e1 : e0;
            num += (trans + em) * mf;
            float n0 = lse2(a0 + T00, a1 + T10) + e0;
            float n1 = lse2(a0 + T01, a1 + T11) + e1;
            if (mt) { a0 = n0; a1 = n1; }
            prev = y;
            msum += mt;
        }
        int last = lab[msum - 1];
        last = (last == -100) ? 0 : last;
        num += ce[last];
        float logZ = lse2(a0 + ce[0], a1 + ce[1]);
        val = num - logZ;
    }
    for (int off = 32; off; off >>= 1) val += __shfl_down(val, off, 64);
    if (threadIdx.x == 0) {
        float span = -(val / (float)BB);
        float kd = kd_sum[0] / (float)(3u * BB * TT * DD);
        out[0] = 0.5f * span + 0.5f * kd;
    }
}

extern "C" void kernel_launch(void* const* d_in, const int* in_sizes, int n_in,
                              void* d_out, int out_size, void* d_ws, size_t ws_size,
                              hipStream_t stream) {
    const float* x    = (const float*)d_in[0];
    const float* sf   = (const float*)d_in[1];
    const float* tfp  = (const float*)d_in[2];
    const float* wif  = (const float*)d_in[3];
    const float* whf  = (const float*)d_in[4];
    const float* bif  = (const float*)d_in[5];
    const float* bhf  = (const float*)d_in[6];
    const float* wib  = (const float*)d_in[7];
    const float* whb  = (const float*)d_in[8];
    const float* bib  = (const float*)d_in[9];
    const float* bhb  = (const float*)d_in[10];
    const float* wcls = (const float*)d_in[11];
    const float* bcls = (const float*)d_in[12];
    const float* cs   = (const float*)d_in[13];
    const float* ce   = (const float*)d_in[14];
    const float* ct   = (const float*)d_in[15];
    const int* labels = (const int*)d_in[16];
    const int* mask   = (const int*)d_in[17];
    float* out = (float*)d_out;

    char* ws = (char*)d_ws;
    ushort* xb   = (ushort*)(ws + OFF_XB);
    ushort* wihb = (ushort*)(ws + OFF_WIH);
    ushort* whhb = (ushort*)(ws + OFF_WHH);
    float* bias  = (float*)(ws + OFF_BIAS);
    ushort* gx   = (ushort*)(ws + OFF_GX);
    ushort* hbuf = (ushort*)(ws + OFF_HB);
    float* lp    = (float*)(ws + OFF_LP);
    int* cnt     = (int*)(ws + OFF_CNT);
    float* kd    = (float*)(ws + OFF_KD);

    prep_kernel<<<1024, 256, 0, stream>>>(x, wif, wib, whf, whb, bif, bhf, bib, bhb,
                                          xb, wihb, whhb, bias, lp, cnt, kd);
    kd_kernel<<<2048, 256, 0, stream>>>((const float4*)sf, (const float4*)tfp, kd,
                                        (int)(3u * BB * TT * DD / 4u));
    gemm_gx<<<dim3(224, 16, 2), 256, 0, stream>>>(xb, wihb, bias, gx);
    lstm_rec<<<dim3(NBX, 2), 256, 0, stream>>>(gx, whhb, wcls, hbuf, cnt, lp);
    crf_loss<<<1, 64, 0, stream>>>(lp, bcls, cs, ce, ct, labels, mask, kd, out);
}

// Round 7
// 2888.113 us; speedup vs baseline: 7.3693x; 1.0365x over previous
//
#include <hip/hip_runtime.h>
#include <hip/hip_bf16.h>

typedef unsigned int uint;
typedef unsigned short ushort;
typedef __attribute__((ext_vector_type(8))) short short8;
typedef __attribute__((ext_vector_type(4))) float floatx4;

// Problem dims
#define BB 32
#define TT 448
#define DD 768
#define HH 256
#define G4 1024          // 4*H
#define BT 14336         // B*T
#define NBX 4            // blocks per direction in lstm_rec
#define NWV 16           // waves per direction (NBX * 4)

// Workspace layout (bytes)
constexpr size_t OFF_XB   = 0;                        // x bf16: BT*D*2 = 22,020,096
constexpr size_t OFF_WIH  = 22020096;                 // wih bf16 (2,1024,768)*2B
constexpr size_t OFF_WHH  = 25165824;                 // whh bf16 (2,1024,256)*2B
constexpr size_t OFF_BIAS = 26214400;                 // bias f32 (2,1024)*4B
constexpr size_t OFF_GX   = 26222592;                 // gx bf16 (2,T,B,1024)*2B = 58,720,256
constexpr size_t OFF_HB   = 84942848;                 // hbuf bf16 (2,449,32,256)*2B = 14,712,832
constexpr size_t OFF_SEQ  = 99655680;                 // seq int (2,449,16) = 57,472, pad 64K
constexpr size_t OFF_LPP  = 99721216;                 // lp_part f32 (448,32,32,2) = 7,340,032
constexpr size_t OFF_LP   = 107061248;                // lp f32 (448,32,2)*4B = 114,688
constexpr size_t OFF_KD   = 107175936;                // kd scalar

__device__ __forceinline__ ushort f2bf(float x) {
    uint u = __float_as_uint(x);
    uint r = (u + 0x7FFFu + ((u >> 16) & 1u)) >> 16;   // RNE, inputs finite
    return (ushort)r;
}
__device__ __forceinline__ float bf2f(ushort s) {
    return __uint_as_float(((uint)s) << 16);
}
__device__ __forceinline__ float fsig(float x) {
    return __builtin_amdgcn_rcpf(1.0f + __expf(-x));
}
__device__ __forceinline__ float ftanh(float x) {
    return 2.0f * __builtin_amdgcn_rcpf(1.0f + __expf(-2.0f * x)) - 1.0f;
}
__device__ __forceinline__ float lse2(float x, float y) {
    float m = fmaxf(x, y);
    return m + logf(expf(x - m) + expf(y - m));
}

// Coherence-point ops (bypass L2 so remote XCDs see them without wbl2/inv)
__device__ __forceinline__ void st_sc1_b64(void* addr, uint2 v) {
    asm volatile("global_store_dwordx2 %0, %1, off sc0 sc1" :: "v"(addr), "v"(v) : "memory");
}
__device__ __forceinline__ void st_sc1_b32(void* addr, int v) {
    asm volatile("global_store_dword %0, %1, off sc0 sc1" :: "v"(addr), "v"(v) : "memory");
}
__device__ __forceinline__ int ld_sc1_b32(const int* addr) {
    int r;
    asm volatile("global_load_dword %0, %1, off sc0 sc1\n\t"
                 "s_waitcnt vmcnt(0)"
                 : "=&v"(r) : "v"(addr) : "memory");
    return r;
}
// Wait for all outstanding vector-memory ops (compiler-opaque stores included)
#define WAIT_VM0() asm volatile("s_waitcnt vmcnt(0)" ::: "memory")

// ---------------- K0: conversions + bias combine + zero seq/kd ----------------
__global__ __launch_bounds__(256) void prep_kernel(
    const float* __restrict__ x,
    const float* __restrict__ wif, const float* __restrict__ wib,
    const float* __restrict__ whf, const float* __restrict__ whb,
    const float* __restrict__ bif, const float* __restrict__ bhf,
    const float* __restrict__ bib, const float* __restrict__ bhb,
    ushort* __restrict__ xb, ushort* __restrict__ wihb,
    ushort* __restrict__ whhb, float* __restrict__ bias,
    int* __restrict__ seq, float* __restrict__ kd_sum)
{
    size_t i0 = (size_t)blockIdx.x * 256 + threadIdx.x;
    if (i0 == 0) kd_sum[0] = 0.f;
    const size_t NX = (size_t)BT * DD;
    const size_t NW = (size_t)G4 * DD;
    const size_t NH = (size_t)G4 * HH;
    const size_t B0 = NX + 2 * NW + 2 * NH;      // bias base
    const size_t B1 = B0 + 2048;                 // seq base
    const size_t TOT = B1 + 2 * 449 * 16;
    const size_t stride = (size_t)gridDim.x * 256;
    for (size_t idx = i0; idx < TOT; idx += stride) {
        if (idx < NX) {
            xb[idx] = f2bf(x[idx]);
        } else if (idx < NX + 2 * NW) {
            size_t j = idx - NX;
            wihb[j] = f2bf(j < NW ? wif[j] : wib[j - NW]);
        } else if (idx < NX + 2 * NW + 2 * NH) {
            size_t j = idx - NX - 2 * NW;
            whhb[j] = f2bf(j < NH ? whf[j] : whb[j - NH]);
        } else if (idx < B1) {
            size_t j = idx - B0;
            bias[j] = (j < 1024) ? (bif[j] + bhf[j]) : (bib[j - 1024] + bhb[j - 1024]);
        } else {
            seq[idx - B1] = 0;
        }
    }
}

// ---------------- K1: KD MSE reduction ----------------
__global__ __launch_bounds__(256) void kd_kernel(
    const float4* __restrict__ s, const float4* __restrict__ t,
    float* __restrict__ kd_sum, int n4)
{
    __shared__ float sred[4];
    float acc = 0.f;
    size_t stride = (size_t)gridDim.x * 256;
    for (size_t i = (size_t)blockIdx.x * 256 + threadIdx.x; i < (size_t)n4; i += stride) {
        float4 a = s[i], b = t[i];
        float d0 = a.x - b.x, d1 = a.y - b.y, d2 = a.z - b.z, d3 = a.w - b.w;
        acc += d0 * d0 + d1 * d1 + d2 * d2 + d3 * d3;
    }
    for (int off = 32; off; off >>= 1) acc += __shfl_down(acc, off, 64);
    int lane = threadIdx.x & 63, wv = threadIdx.x >> 6;
    if (lane == 0) sred[wv] = acc;
    __syncthreads();
    if (threadIdx.x == 0) atomicAdd(kd_sum, sred[0] + sred[1] + sred[2] + sred[3]);
}

// ---------------- K2: gx = x @ W_ih^T + bias, bf16 MFMA, out layout [dir][t][b][1024] ----------------
__global__ __launch_bounds__(256) void gemm_gx(
    const ushort* __restrict__ xb, const ushort* __restrict__ wih,
    const float* __restrict__ bias, ushort* __restrict__ gx)
{
    int dir = blockIdx.z;
    const ushort* W = wih + (size_t)dir * G4 * DD;
    ushort* out = gx + (size_t)dir * BT * G4;
    int tid = threadIdx.x;
    int wave = tid >> 6, lane = tid & 63;
    int quad = lane >> 4, r16 = lane & 15;
    int m0 = blockIdx.x * 64 + wave * 16;
    int n0 = blockIdx.y * 64;
    floatx4 acc[4];
    #pragma unroll
    for (int i = 0; i < 4; i++) acc[i] = (floatx4){0.f, 0.f, 0.f, 0.f};

    const ushort* aptr = xb + (size_t)(m0 + r16) * DD + quad * 8;
    const ushort* bptr = W + (size_t)(n0 + r16) * DD + quad * 8;
    for (int k = 0; k < DD; k += 32) {
        short8 af = *(const short8*)(aptr + k);
        #pragma unroll
        for (int nt = 0; nt < 4; nt++) {
            short8 bf = *(const short8*)(bptr + (size_t)nt * 16 * DD + k);
            acc[nt] = __builtin_amdgcn_mfma_f32_16x16x32_bf16(af, bf, acc[nt], 0, 0, 0);
        }
    }
    #pragma unroll
    for (int nt = 0; nt < 4; nt++) {
        int col = n0 + nt * 16 + r16;
        float bv = bias[dir * G4 + col];
        #pragma unroll
        for (int i = 0; i < 4; i++) {
            int row = m0 + quad * 4 + i;
            int b = row / TT, t = row % TT;     // tiles never straddle b (448 = 7*64)
            out[((size_t)t * BB + b) * G4 + col] = f2bf(acc[nt][i] + bv);
        }
    }
}

// ---------------- K3: LSTM recurrence, wave-autonomous, sc1 h-exchange ----------------
// grid (NBX,2) x 256 thr.  Wave (bx,w) owns d-slice dbase..dbase+15, all 4 gates.
// A = W_hh fragments (register-resident), B = h fragments (sc1 loads), D = gates^T.
// Per-producer-wave seq words (plain sc1 stores); consumers poll all 16 with one
// 16-lane gather + ballot.  Zero atomics in the loop; logits -> lp_part slots.
__global__ __launch_bounds__(256, 1) void lstm_rec(
    const ushort* __restrict__ gxall,   // [2][T][B][1024] bf16
    const ushort* __restrict__ whhb,    // [2][1024][256] bf16
    const float* __restrict__ Wcls,     // [2][512] f32
    ushort* __restrict__ hbuf,          // [2][449][32][256] bf16
    int* __restrict__ seq,              // [2][449][16]
    float* __restrict__ lp_part)        // [448][32][32][2] f32
{
    int bx = blockIdx.x;
    int dir = blockIdx.y;
    int tid = threadIdx.x;
    int w = tid >> 6, lane = tid & 63;
    int quad = lane >> 4, r16 = lane & 15;
    int dbase = bx * 64 + w * 16;       // this wave's 16 h-dims
    int slot = dir * 16 + bx * 4 + w;   // global wave slot (0..31)

    // A-operand W fragments: A[m=r16][k=kt*32+quad*8+j], row = g*256+dbase+r16
    short8 wfrag[4][8];
    const ushort* wsrc = whhb + (size_t)dir * (G4 * HH);
    #pragma unroll
    for (int g = 0; g < 4; g++)
        #pragma unroll
        for (int kt = 0; kt < 8; kt++)
            wfrag[g][kt] = *(const short8*)(wsrc + (size_t)(g * 256 + dbase + r16) * HH + kt * 32 + quad * 8);

    float wc0[4], wc1[4];
    #pragma unroll
    for (int r = 0; r < 4; r++) {
        int d = dbase + quad * 4 + r;
        wc0[r] = Wcls[dir * 256 + d];
        wc1[r] = Wcls[512 + dir * 256 + d];
    }
    float cst[2][4];
    #pragma unroll
    for (int mt = 0; mt < 2; mt++)
        #pragma unroll
        for (int r = 0; r < 4; r++) cst[mt][r] = 0.f;

    const ushort* gxd = gxall + (size_t)dir * BT * G4;
    ushort* hb = hbuf + (size_t)dir * 449 * BB * HH;
    int* sq = seq + dir * 449 * 16;

    for (int s = 0; s < TT; s++) {
        int t = dir ? (TT - 1 - s) : s;
        // gx prefetch (issued before the poll; compiler waits at first use)
        uint2 gxv[4][2];
        #pragma unroll
        for (int g = 0; g < 4; g++)
            #pragma unroll
            for (int mt = 0; mt < 2; mt++)
                gxv[g][mt] = *(const uint2*)(gxd + ((size_t)t * BB + mt * 16 + r16) * G4
                                             + g * 256 + dbase + quad * 4);

        floatx4 acc[4][2];
        #pragma unroll
        for (int g = 0; g < 4; g++)
            #pragma unroll
            for (int mt = 0; mt < 2; mt++)
                acc[g][mt] = (floatx4){
                    bf2f((ushort)(gxv[g][mt].x & 0xFFFFu)),
                    bf2f((ushort)(gxv[g][mt].x >> 16)),
                    bf2f((ushort)(gxv[g][mt].y & 0xFFFFu)),
                    bf2f((ushort)(gxv[g][mt].y >> 16))};

        if (s > 0) {
            // 16-wide producer poll: one sc1 gather of one 64B line + ballot
            const int* pa = sq + s * 16 + (lane & 15);
            for (;;) {
                int v = ld_sc1_b32(pa);
                if (__ballot(v != 0) == ~0ull) break;
            }
            const ushort* hsrc = hb + (size_t)s * (BB * HH);
            const ushort* h0 = hsrc + (size_t)r16 * HH + quad * 8;
            const ushort* h1 = hsrc + (size_t)(16 + r16) * HH + quad * 8;
            int4 hA0, hA1, hA2, hA3, hA4, hA5, hA6, hA7;
            int4 hB0, hB1, hB2, hB3, hB4, hB5, hB6, hB7;
            // One asm block: 16 coherence-point loads + waitcnt. Early-clobber
            // outputs keep them disjoint from address inputs (plain "=v"
            // aliased -> GPU fault in R5). MFMAs data-depend on the outputs.
            asm volatile(
                "global_load_dwordx4 %0, %16, off sc0 sc1\n\t"
                "global_load_dwordx4 %1, %16, off offset:64 sc0 sc1\n\t"
                "global_load_dwordx4 %2, %16, off offset:128 sc0 sc1\n\t"
                "global_load_dwordx4 %3, %16, off offset:192 sc0 sc1\n\t"
                "global_load_dwordx4 %4, %16, off offset:256 sc0 sc1\n\t"
                "global_load_dwordx4 %5, %16, off offset:320 sc0 sc1\n\t"
                "global_load_dwordx4 %6, %16, off offset:384 sc0 sc1\n\t"
                "global_load_dwordx4 %7, %16, off offset:448 sc0 sc1\n\t"
                "global_load_dwordx4 %8, %17, off sc0 sc1\n\t"
                "global_load_dwordx4 %9, %17, off offset:64 sc0 sc1\n\t"
                "global_load_dwordx4 %10, %17, off offset:128 sc0 sc1\n\t"
                "global_load_dwordx4 %11, %17, off offset:192 sc0 sc1\n\t"
                "global_load_dwordx4 %12, %17, off offset:256 sc0 sc1\n\t"
                "global_load_dwordx4 %13, %17, off offset:320 sc0 sc1\n\t"
                "global_load_dwordx4 %14, %17, off offset:384 sc0 sc1\n\t"
                "global_load_dwordx4 %15, %17, off offset:448 sc0 sc1\n\t"
                "s_waitcnt vmcnt(0)"
                : "=&v"(hA0), "=&v"(hA1), "=&v"(hA2), "=&v"(hA3),
                  "=&v"(hA4), "=&v"(hA5), "=&v"(hA6), "=&v"(hA7),
                  "=&v"(hB0), "=&v"(hB1), "=&v"(hB2), "=&v"(hB3),
                  "=&v"(hB4), "=&v"(hB5), "=&v"(hB6), "=&v"(hB7)
                : "v"(h0), "v"(h1)
                : "memory");
            short8 hf[2][8];
            hf[0][0] = *(short8*)&hA0; hf[0][1] = *(short8*)&hA1;
            hf[0][2] = *(short8*)&hA2; hf[0][3] = *(short8*)&hA3;
            hf[0][4] = *(short8*)&hA4; hf[0][5] = *(short8*)&hA5;
            hf[0][6] = *(short8*)&hA6; hf[0][7] = *(short8*)&hA7;
            hf[1][0] = *(short8*)&hB0; hf[1][1] = *(short8*)&hB1;
            hf[1][2] = *(short8*)&hB2; hf[1][3] = *(short8*)&hB3;
            hf[1][4] = *(short8*)&hB4; hf[1][5] = *(short8*)&hB5;
            hf[1][6] = *(short8*)&hB6; hf[1][7] = *(short8*)&hB7;
            #pragma unroll
            for (int kt = 0; kt < 8; kt++)
                #pragma unroll
                for (int g = 0; g < 4; g++)
                    #pragma unroll
                    for (int mt = 0; mt < 2; mt++)
                        acc[g][mt] = __builtin_amdgcn_mfma_f32_16x16x32_bf16(
                            wfrag[g][kt], hf[mt][kt], acc[g][mt], 0, 0, 0);
        }

        // Epilogue: D row (quad*4+r) = d-offset, col r16 = batch (mt picks b or b+16)
        ushort* hdst = hb + (size_t)(s + 1) * (BB * HH);
        float lv0[2], lv1[2];
        #pragma unroll
        for (int mt = 0; mt < 2; mt++) {
            float l0 = 0.f, l1 = 0.f;
            uint pk[2];
            #pragma unroll
            for (int r = 0; r < 4; r++) {
                float ig = fsig(acc[0][mt][r]);
                float fg = fsig(acc[1][mt][r]);
                float gg = ftanh(acc[2][mt][r]);
                float og = fsig(acc[3][mt][r]);
                float c = fg * cst[mt][r] + ig * gg;
                cst[mt][r] = c;
                float h = og * ftanh(c);
                uint hb16 = (uint)f2bf(h);
                if (r & 1) pk[r >> 1] |= hb16 << 16; else pk[r >> 1] = hb16;
                l0 += h * wc0[r];
                l1 += h * wc1[r];
            }
            st_sc1_b64(hdst + (size_t)(mt * 16 + r16) * HH + dbase + quad * 4,
                       make_uint2(pk[0], pk[1]));
            lv0[mt] = l0; lv1[mt] = l1;
        }
        WAIT_VM0();   // h stores acked at coherence point before seq flag
        if (lane == 0) st_sc1_b32(sq + (s + 1) * 16 + bx * 4 + w, 1);

        // logit partials: per-wave slot, plain cached stores, off critical path
        #pragma unroll
        for (int mt = 0; mt < 2; mt++) {
            lv0[mt] += __shfl_xor(lv0[mt], 16, 64);
            lv0[mt] += __shfl_xor(lv0[mt], 32, 64);
            lv1[mt] += __shfl_xor(lv1[mt], 16, 64);
            lv1[mt] += __shfl_xor(lv1[mt], 32, 64);
        }
        if (quad == 0) {
            #pragma unroll
            for (int mt = 0; mt < 2; mt++) {
                int b = mt * 16 + r16;
                *(float2*)(lp_part + ((size_t)(t * 32 + slot) * 32 + b) * 2) =
                    make_float2(lv0[mt], lv1[mt]);
            }
        }
    }
}

// ---------------- K3b: reduce lp_part slots -> lp ----------------
__global__ __launch_bounds__(64) void lp_sum(
    const float* __restrict__ lp_part, float* __restrict__ lp)
{
    int t = blockIdx.x;
    int tid = threadIdx.x;            // tid = b*2 + tag
    const float* p = lp_part + (size_t)t * 2048 + tid;
    float s = 0.f;
    #pragma unroll
    for (int k = 0; k < 32; k++) s += p[k * 64];
    lp[(size_t)t * 64 + tid] = s;
}

// ---------------- K4: CRF numerator + logZ + final loss ----------------
__global__ void crf_loss(
    const float* __restrict__ lp, const float* __restrict__ bcls,
    const float* __restrict__ cs, const float* __restrict__ ce,
    const float* __restrict__ ct, const int* __restrict__ labels,
    const int* __restrict__ mask, const float* __restrict__ kd_sum,
    float* __restrict__ out)
{
    int b = threadIdx.x;
    float val = 0.f;
    if (b < BB) {
        float bc0 = bcls[0], bc1 = bcls[1];
        float T00 = ct[0], T01 = ct[1], T10 = ct[2], T11 = ct[3];
        const int* lab = labels + (size_t)b * TT;
        const int* mk = mask + (size_t)b * TT;

        float e0 = lp[(size_t)b * 2 + 0] + bc0;
        float e1 = lp[(size_t)b * 2 + 1] + bc1;
        int y0 = lab[0];
        y0 = (y0 == -100) ? 0 : y0;
        float num = cs[y0] + (y0 ? e1 : e0);
        float a0 = cs[0] + e0, a1 = cs[1] + e1;
        int prev = y0;
        int msum = 1;
        for (int t = 1; t < TT; t++) {
            e0 = lp[((size_t)t * BB + b) * 2 + 0] + bc0;
            e1 = lp[((size_t)t * BB + b) * 2 + 1] + bc1;
            int y = lab[t];
            y = (y == -100) ? 0 : y;
            int mt = (mk[t] != 0);
            float mf = mt ? 1.f : 0.f;
            float trans = ct[prev * 2 + y];
            float em = y ? e1 : e0;
            num += (trans + em) * mf;
            float n0 = lse2(a0 + T00, a1 + T10) + e0;
            float n1 = lse2(a0 + T01, a1 + T11) + e1;
            if (mt) { a0 = n0; a1 = n1; }
            prev = y;
            msum += mt;
        }
        int last = lab[msum - 1];
        last = (last == -100) ? 0 : last;
        num += ce[last];
        float logZ = lse2(a0 + ce[0], a1 + ce[1]);
        val = num - logZ;
    }
    for (int off = 32; off; off >>= 1) val += __shfl_down(val, off, 64);
    if (threadIdx.x == 0) {
        float span = -(val / (float)BB);
        float kd = kd_sum[0] / (float)(3u * BB * TT * DD);
        out[0] = 0.5f * span + 0.5f * kd;
    }
}

extern "C" void kernel_launch(void* const* d_in, const int* in_sizes, int n_in,
                              void* d_out, int out_size, void* d_ws, size_t ws_size,
                              hipStream_t stream) {
    const float* x    = (const float*)d_in[0];
    const float* sf   = (const float*)d_in[1];
    const float* tfp  = (const float*)d_in[2];
    const float* wif  = (const float*)d_in[3];
    const float* whf  = (const float*)d_in[4];
    const float* bif  = (const float*)d_in[5];
    const float* bhf  = (const float*)d_in[6];
    const float* wib  = (const float*)d_in[7];
    const float* whb  = (const float*)d_in[8];
    const float* bib  = (const float*)d_in[9];
    const float* bhb  = (const float*)d_in[10];
    const float* wcls = (const float*)d_in[11];
    const float* bcls = (const float*)d_in[12];
    const float* cs   = (const float*)d_in[13];
    const float* ce   = (const float*)d_in[14];
    const float* ct   = (const float*)d_in[15];
    const int* labels = (const int*)d_in[16];
    const int* mask   = (const int*)d_in[17];
    float* out = (float*)d_out;

    char* ws = (char*)d_ws;
    ushort* xb    = (ushort*)(ws + OFF_XB);
    ushort* wihb  = (ushort*)(ws + OFF_WIH);
    ushort* whhb  = (ushort*)(ws + OFF_WHH);
    float* bias   = (float*)(ws + OFF_BIAS);
    ushort* gx    = (ushort*)(ws + OFF_GX);
    ushort* hbuf  = (ushort*)(ws + OFF_HB);
    int* seq      = (int*)(ws + OFF_SEQ);
    float* lppart = (float*)(ws + OFF_LPP);
    float* lp     = (float*)(ws + OFF_LP);
    float* kd     = (float*)(ws + OFF_KD);

    prep_kernel<<<1024, 256, 0, stream>>>(x, wif, wib, whf, whb, bif, bhf, bib, bhb,
                                          xb, wihb, whhb, bias, seq, kd);
    kd_kernel<<<2048, 256, 0, stream>>>((const float4*)sf, (const float4*)tfp, kd,
                                        (int)(3u * BB * TT * DD / 4u));
    gemm_gx<<<dim3(224, 16, 2), 256, 0, stream>>>(xb, wihb, bias, gx);
    lstm_rec<<<dim3(NBX, 2), 256, 0, stream>>>(gx, whhb, wcls, hbuf, seq, lppart);
    lp_sum<<<448, 64, 0, stream>>>(lppart, lp);
    crf_loss<<<1, 64, 0, stream>>>(lp, bcls, cs, ce, ct, labels, mask, kd, out);
}